// Round 13
// baseline (534.207 us; speedup 1.0000x reference)
//
#include <hip/hip_runtime.h>
#include <hip/hip_bf16.h>

typedef unsigned int uint;
typedef unsigned short ushort;

using s16x8 = __attribute__((ext_vector_type(8))) short;
using f32x4 = __attribute__((ext_vector_type(4))) float;

#define NPIX 65536   // 16 * 64 * 64 pixels

// ---------- helpers ----------
__device__ __forceinline__ ushort f2bf(float f) {
    uint u = __float_as_uint(f);
    u += 0x7fffu + ((u >> 16) & 1u);   // RNE
    return (ushort)(u >> 16);
}
__device__ __forceinline__ float bf2f(uint h) { return __uint_as_float(h << 16); }
__device__ __forceinline__ uint pk2bf(float a, float b) {      // v_cvt_pk_bf16_f32 (RNE)
    float2 f2; f2.x = a; f2.y = b;
    __hip_bfloat162 h = __float22bfloat162_rn(f2);
    return *(reinterpret_cast<uint*>(&h));
}

__device__ __forceinline__ void async16(const void* g, void* l) {
    __builtin_amdgcn_global_load_lds(
        (const __attribute__((address_space(1))) void*)g,
        (__attribute__((address_space(3))) void*)l, 16, 0, 0);
}

#define VMW4 asm volatile("s_waitcnt vmcnt(4)" ::: "memory")
#define VMW0 asm volatile("s_waitcnt vmcnt(0)" ::: "memory")
#define LKM0 asm volatile("s_waitcnt lgkmcnt(0)" ::: "memory")
#define NOP2 (void)0

// 8-phase phase macro (gemm_reg): 4 A-frag ds_reads, stage stmt, optional vmcnt,
// barrier, prio-wrapped 16 MFMA, barrier.  (T3+T4+T5 per guide §5.5)
#define DOPH(m0_, m1_, STG, VMW) do {                                             \
        s16x8 af0_[2], af1_[2];                                                   \
        af0_[0] = AFR(m0_, 0); af0_[1] = AFR(m0_, 1);                             \
        af1_[0] = AFR(m1_, 0); af1_[1] = AFR(m1_, 1);                             \
        STG;                                                                      \
        VMW;                                                                      \
        __builtin_amdgcn_s_barrier();                                             \
        __builtin_amdgcn_s_setprio(1);                                            \
        _Pragma("unroll") for (int ni_ = 0; ni_ < 4; ++ni_) {                     \
            _Pragma("unroll") for (int ks_ = 0; ks_ < 2; ++ks_)                   \
                acc[m0_][ni_] = __builtin_amdgcn_mfma_f32_16x16x32_bf16(          \
                    af0_[ks_], bfr[ni_][ks_], acc[m0_][ni_], 0, 0, 0);            \
            _Pragma("unroll") for (int ks_ = 0; ks_ < 2; ++ks_)                   \
                acc[m1_][ni_] = __builtin_amdgcn_mfma_f32_16x16x32_bf16(          \
                    af1_[ks_], bfr[ni_][ks_], acc[m1_][ni_], 0, 0, 0);            \
        }                                                                         \
        __builtin_amdgcn_s_setprio(0);                                            \
        __builtin_amdgcn_s_barrier();                                             \
    } while (0)

// ---------- prep: weight cvt + stats zero ----------
__global__ __launch_bounds__(256) void prep(const float* __restrict__ w_in, const float* __restrict__ w_emb,
                                            const float* __restrict__ w_out,
                                            ushort* __restrict__ o1, ushort* __restrict__ o2,
                                            ushort* __restrict__ o3, float* __restrict__ stats) {
    int id = blockIdx.x, t = threadIdx.x;
    if (id < 4224) {                                   // weight convert
        int i = id * 256 + t;
        if (i < 524288) {                              // w_in 512x1024
            o1[i] = f2bf(w_in[i]);
        } else if (i < 819200) {                       // w_emb 512x576 (537 real, pad 0)
            int j = i - 524288;
            int r = j / 576, c = j - r * 576;
            o2[j] = (c < 537) ? f2bf(w_emb[(size_t)r * 537 + c]) : (ushort)0;
        } else {                                       // w_out 512x512
            int j = i - 819200;
            o3[j] = f2bf(w_out[j]);
        }
    } else {                                           // zero stats (3*1024 f32)
#pragma unroll
        for (int r = 0; r < 12; ++r) stats[r * 256 + t] = 0.f;
    }
}

// ---------- GEMM1 (TN): 128x128/BK=64, 4-phase counted-vmcnt, 3 independent blocks/CU ----------
// R12 lesson: occupancy alone (2-phase) loses; R11 lesson: 8-phase at 1 block/CU is
// latency-bound.  Combine: 4 waves, A single-buffered (frags->regs at tile start), B dbuf,
// 48KB LDS -> 3 blocks/CU.  vmcnt: WRITEX's register-dep wait (FIFO) confirms all older
// B loads => B(kt+1) landed at ph2 of kt.  Writer lgkmcnt(0) before ph2 barrier makes
// A-writes visible to all waves at tile kt+1 start.
__global__ __launch_bounds__(256, 3) void gemm1_tn(const float* __restrict__ x, const ushort* __restrict__ Bw,
                                                   ushort* __restrict__ C, float* __restrict__ st) {
    const int K = 1024, NT = 16;
    __shared__ ushort Asm[128][64];
    __shared__ ushort Bsm[2][128][64];

    int id = blockIdx.x;                       // 2048 blocks
    int xcd = id & 7, slot = id >> 3;          // XCD chunking: 64 M-panels x 4 N each
    int row0 = (xcd * 64 + (slot >> 2)) * 128, col0 = (slot & 3) * 128;

    int t = threadIdx.x, wv = t >> 6, lane = t & 63;
    int wr = wv >> 1, wc = wv & 1;             // wave grid 2M x 2N, each 64x64 out
    int g = lane >> 4, rr = lane & 15;
    int swzl = (rr & 7) << 4;

    // B staging (async16, pre-swizzled source)
    int srow = t >> 3;
    int scol = ((t & 7) * 16) ^ ((srow & 7) << 4);
    const ushort* pb = Bw + (size_t)(col0 + srow) * K + (scol >> 1);

    // A staging from x: thread covers c = c0..c0+3, s = srel..srel+7
    int c0 = (lane & 15) * 4;
    int srel = wv * 32 + (lane >> 4) * 8;
    const float* px = x + (((size_t)(row0 >> 12) * 1024) << 12) + (row0 & 4095) + srel;

    const f32x4 fz = {0.f, 0.f, 0.f, 0.f};
    f32x4 acc[4][4];
#pragma unroll
    for (int i = 0; i < 4; ++i)
#pragma unroll
        for (int j = 0; j < 4; ++j) acc[i][j] = fz;

    float4 LA[4][2];

#define STB2(d_, kt_, q0_, q1_) do {                                              \
        async16(pb + (size_t)((q0_) * 32) * K + (kt_) * 64, &Bsm[d_][(q0_) * 32 + wv * 8][0]); \
        async16(pb + (size_t)((q1_) * 32) * K + (kt_) * 64, &Bsm[d_][(q1_) * 32 + wv * 8][0]); \
    } while (0)
#define LOADX1(kt_) do {                                                          \
        _Pragma("unroll") for (int i_ = 0; i_ < 4; ++i_)                          \
        _Pragma("unroll") for (int j_ = 0; j_ < 2; ++j_)                          \
            LA[i_][j_] = *(const float4*)&px[(((size_t)((kt_) * 64 + c0 + i_)) << 12) + j_ * 4]; \
    } while (0)
#define WRITEX1() do {                                                            \
        _Pragma("unroll") for (int sj_ = 0; sj_ < 8; ++sj_) {                     \
            int r_ = srel + sj_;                                                  \
            float e0_ = ((const float*)&LA[0][sj_ >> 2])[sj_ & 3];                \
            float e1_ = ((const float*)&LA[1][sj_ >> 2])[sj_ & 3];                \
            float e2_ = ((const float*)&LA[2][sj_ >> 2])[sj_ & 3];                \
            float e3_ = ((const float*)&LA[3][sj_ >> 2])[sj_ & 3];                \
            uint2 pk_;                                                            \
            pk_.x = pk2bf(e0_, e1_);                                              \
            pk_.y = pk2bf(e2_, e3_);                                              \
            *(uint2*)((char*)&Asm[r_][0] + ((c0 * 2) ^ ((sj_ & 7) << 4))) = pk_;  \
        }                                                                         \
    } while (0)
#define MFMAPH(mi_) do {                                                          \
        __builtin_amdgcn_s_barrier();                                             \
        __builtin_amdgcn_s_setprio(1);                                            \
        _Pragma("unroll") for (int ni_ = 0; ni_ < 4; ++ni_)                       \
            _Pragma("unroll") for (int ks_ = 0; ks_ < 2; ++ks_)                   \
                acc[mi_][ni_] = __builtin_amdgcn_mfma_f32_16x16x32_bf16(          \
                    af[mi_][ks_], bfr[ni_][ks_], acc[mi_][ni_], 0, 0, 0);         \
        __builtin_amdgcn_s_setprio(0);                                            \
        __builtin_amdgcn_s_barrier();                                             \
    } while (0)

    // prologue: tile0 A -> regs -> Asm; B(0),B(1) async
    LOADX1(0);
    STB2(0, 0, 0, 1); STB2(0, 0, 2, 3);
    STB2(1, 1, 0, 1); STB2(1, 1, 2, 3);
    WRITEX1();                                  // reg-dep wait drains A0 loads
    VMW4;                                       // B(0) confirmed; B(1) in flight
    LKM0;                                       // drain ds_writes
    __builtin_amdgcn_s_barrier();

    for (int kt = 0; kt < NT; ++kt) {
        int d = kt & 1;
        s16x8 af[4][2], bfr[4][2];
#pragma unroll
        for (int mi = 0; mi < 4; ++mi)
#pragma unroll
            for (int ks = 0; ks < 2; ++ks)
                af[mi][ks] = *(const s16x8*)&Asm[wr * 64 + mi * 16 + rr][((ks * 64 + g * 16) ^ swzl) >> 1];
#pragma unroll
        for (int ni = 0; ni < 4; ++ni)
#pragma unroll
            for (int ks = 0; ks < 2; ++ks)
                bfr[ni][ks] = *(const s16x8*)&Bsm[d][wc * 64 + ni * 16 + rr][((ks * 64 + g * 16) ^ swzl) >> 1];

        if (kt + 1 < NT) LOADX1(kt + 1);        // ph0 stage: issue next A loads
        MFMAPH(0);
        if (kt + 2 < NT) STB2(d, kt + 2, 0, 1); // ph1 stage: B(kt+2) first half
        MFMAPH(1);
        if (kt + 1 < NT) { WRITEX1(); LKM0; }   // ph2: drains A-loads (and older B, FIFO)
        MFMAPH(2);
        if (kt + 2 < NT) STB2(d, kt + 2, 2, 3); // ph3 stage: B(kt+2) second half
        VMW4;
        MFMAPH(3);
    }
#undef STB2
#undef LOADX1
#undef WRITEX1
#undef MFMAPH

    // C write (C/D layout: col = lane&15, row = (lane>>4)*4 + reg) + fused stats
#pragma unroll
    for (int mi = 0; mi < 4; ++mi)
#pragma unroll
        for (int ni = 0; ni < 4; ++ni)
#pragma unroll
            for (int e2 = 0; e2 < 4; ++e2) {
                int row = row0 + wr * 64 + mi * 16 + g * 4 + e2;
                int col = col0 + wc * 64 + ni * 16 + rr;
                C[(size_t)row * 512 + col] = f2bf(acc[mi][ni][e2]);
            }
#pragma unroll
    for (int ni = 0; ni < 4; ++ni) {
        float s = 0.f, q = 0.f;
#pragma unroll
        for (int mi = 0; mi < 4; ++mi)
#pragma unroll
            for (int e2 = 0; e2 < 4; ++e2) {
                float v = acc[mi][ni][e2];
                s += v; q += v * v;
            }
        s += __shfl_xor(s, 16); s += __shfl_xor(s, 32);
        q += __shfl_xor(q, 16); q += __shfl_xor(q, 32);
        if (lane < 16) {
            int col = col0 + wc * 64 + ni * 16 + rr;
            atomicAdd(st + col, s);
            atomicAdd(st + 512 + col, q);
        }
    }
}

// ---------- GEMM2/3: 8-phase engine + reg-staged A with fused BN+ReLU (coefs from stats) ----------
__global__ __launch_bounds__(512, 2) void gemm_reg(const ushort* __restrict__ Araw, const ushort* __restrict__ gsrc,
                                                   const ushort* __restrict__ Bw, ushort* __restrict__ C,
                                                   int Kb, int NT,
                                                   const float* __restrict__ stin, const float* __restrict__ gamma,
                                                   const float* __restrict__ beta, float* __restrict__ stout) {
    __shared__ ushort Asm[2][2][128][64];
    __shared__ ushort Bsm[2][2][128][64];

    int id = blockIdx.x;
    int swz = (id & 7) * 64 + (id >> 3);
    int row0 = (swz >> 1) * 256, col0 = (swz & 1) * 256;

    int t = threadIdx.x, wv = t >> 6, lane = t & 63;
    int wr = wv >> 2, wc = wv & 3;
    int g = lane >> 4, rr = lane & 15;
    int swzl = (rr & 7) << 4;

    int srow = t >> 3;
    int kb = (t & 7) * 16;                         // logical col byte within 128B k-row
    int scol = kb ^ ((srow & 7) << 4);             // pre-swizzled (async paths)
    const ushort* pb = Bw + (size_t)(col0 + srow) * Kb + (scol >> 1);
    const ushort* pg = gsrc + (size_t)(row0 + srow) * 64 + (scol >> 1);
    int wofs = scol >> 1;                          // swizzled LDS elem offset for reg writes

    const f32x4 fz = {0.f, 0.f, 0.f, 0.f};
    f32x4 acc[8][4];
#pragma unroll
    for (int i = 0; i < 8; ++i)
#pragma unroll
        for (int j = 0; j < 4; ++j) acc[i][j] = fz;

    uint4 rq0, rq1, rq2, rq3;
    float scq[8], shq[8];

#define STB(d_, h_, kt_) do {                                                     \
        async16(pb + (size_t)((h_) * 128) * Kb + (kt_) * 64,      &Bsm[d_][h_][wv * 8][0]);      \
        async16(pb + (size_t)((h_) * 128 + 64) * Kb + (kt_) * 64, &Bsm[d_][h_][64 + wv * 8][0]); \
    } while (0)
#define GSTAGE(d_) do {                                                           \
        async16(pg,             &Asm[d_][0][wv * 8][0]);                          \
        async16(pg + 64 * 64,   &Asm[d_][0][64 + wv * 8][0]);                     \
        async16(pg + 128 * 64,  &Asm[d_][1][wv * 8][0]);                          \
        async16(pg + 192 * 64,  &Asm[d_][1][64 + wv * 8][0]);                     \
    } while (0)
#define LOADQ(kt_) do { int c0_ = (kt_) * 64 + (t & 7) * 8;                       \
        float4 m1_ = *(const float4*)&stin[c0_], m2_ = *(const float4*)&stin[c0_ + 4]; \
        float4 v1_ = *(const float4*)&stin[512 + c0_], v2_ = *(const float4*)&stin[512 + c0_ + 4]; \
        float4 g1_ = *(const float4*)&gamma[c0_], g2_ = *(const float4*)&gamma[c0_ + 4]; \
        float4 b1_ = *(const float4*)&beta[c0_],  b2_ = *(const float4*)&beta[c0_ + 4]; \
        float mm_[8] = {m1_.x, m1_.y, m1_.z, m1_.w, m2_.x, m2_.y, m2_.z, m2_.w};  \
        float vv_[8] = {v1_.x, v1_.y, v1_.z, v1_.w, v2_.x, v2_.y, v2_.z, v2_.w};  \
        float gg_[8] = {g1_.x, g1_.y, g1_.z, g1_.w, g2_.x, g2_.y, g2_.z, g2_.w};  \
        float bb_[8] = {b1_.x, b1_.y, b1_.z, b1_.w, b2_.x, b2_.y, b2_.z, b2_.w};  \
        _Pragma("unroll") for (int j_ = 0; j_ < 8; ++j_) {                        \
            float mean_ = mm_[j_] * (1.f / 65536.f);                              \
            float var_ = vv_[j_] * (1.f / 65536.f) - mean_ * mean_;               \
            float s_ = rsqrtf(var_ + 1e-5f) * gg_[j_];                            \
            scq[j_] = s_; shq[j_] = bb_[j_] - mean_ * s_;                         \
        }                                                                         \
        const ushort* pa_ = Araw + (size_t)(row0 + srow) * 512 + c0_;             \
        rq0 = *(const uint4*)(pa_);                                               \
        rq1 = *(const uint4*)(pa_ + 64 * 512);                                    \
        rq2 = *(const uint4*)(pa_ + 128 * 512);                                   \
        rq3 = *(const uint4*)(pa_ + 192 * 512);                                   \
    } while (0)
#define XFORM1(rv) do {                                                           \
        uint w_[4]; uint in_[4] = {rv.x, rv.y, rv.z, rv.w};                       \
        _Pragma("unroll") for (int p_ = 0; p_ < 4; ++p_) {                        \
            float a_ = fmaxf(bf2f(in_[p_] & 0xffffu) * scq[p_ * 2] + shq[p_ * 2], 0.f); \
            float b_ = fmaxf(bf2f(in_[p_] >> 16) * scq[p_ * 2 + 1] + shq[p_ * 2 + 1], 0.f); \
            w_[p_] = pk2bf(a_, b_);                                               \
        }                                                                         \
        rv.x = w_[0]; rv.y = w_[1]; rv.z = w_[2]; rv.w = w_[3];                   \
    } while (0)
#define WRITEQ(d_) do {                                                           \
        XFORM1(rq0); XFORM1(rq1); XFORM1(rq2); XFORM1(rq3);                       \
        *(uint4*)&Asm[d_][0][srow][wofs]      = rq0;                              \
        *(uint4*)&Asm[d_][0][srow + 64][wofs] = rq1;                              \
        *(uint4*)&Asm[d_][1][srow][wofs]      = rq2;                              \
        *(uint4*)&Asm[d_][1][srow + 64][wofs] = rq3;                              \
    } while (0)
#define AFR(m_, ks_) (*(const s16x8*)&Asm[d][wr][(m_) * 16 + rr][(((ks_) * 64 + g * 16) ^ swzl) >> 1])

    LOADQ(0);
    STB(0, 0, 0); STB(0, 1, 0); STB(1, 0, 1); STB(1, 1, 1);
    WRITEQ(0);
    VMW4;
    LKM0;
    __builtin_amdgcn_s_barrier();

    for (int kt = 0; kt < NT; ++kt) {
        int d = kt & 1, e = d ^ 1;
        s16x8 bfr[4][2];
#pragma unroll
        for (int ni = 0; ni < 4; ++ni)
#pragma unroll
            for (int ks = 0; ks < 2; ++ks)
                bfr[ni][ks] = *(const s16x8*)&Bsm[d][wc >> 1][(wc & 1) * 64 + ni * 16 + rr][((ks * 64 + g * 16) ^ swzl) >> 1];
        DOPH(0, 1, { if (kt + 1 < NT) { if (kt + 1 < 8) LOADQ(kt + 1); else GSTAGE(e); } }, NOP2);
        DOPH(2, 3, NOP2, NOP2);
        DOPH(4, 5, { if (kt + 1 < 8) WRITEQ(e); if (kt + 2 < NT) STB(d, 0, kt + 2); }, NOP2);
        DOPH(6, 7, if (kt + 2 < NT) STB(d, 1, kt + 2), { if (kt == NT - 2) { VMW0; } else { VMW4; } });
    }
#undef STB
#undef GSTAGE
#undef LOADQ
#undef XFORM1
#undef WRITEQ
#undef AFR

#pragma unroll
    for (int mi = 0; mi < 8; ++mi)
#pragma unroll
        for (int ni = 0; ni < 4; ++ni)
#pragma unroll
            for (int e2 = 0; e2 < 4; ++e2) {
                int row = row0 + wr * 128 + mi * 16 + g * 4 + e2;
                int col = col0 + wc * 64 + ni * 16 + rr;
                C[(size_t)row * 512 + col] = f2bf(acc[mi][ni][e2]);
            }
#pragma unroll
    for (int ni = 0; ni < 4; ++ni) {
        float s = 0.f, q = 0.f;
#pragma unroll
        for (int mi = 0; mi < 8; ++mi)
#pragma unroll
            for (int e2 = 0; e2 < 4; ++e2) {
                float v = acc[mi][ni][e2];
                s += v; q += v * v;
            }
        s += __shfl_xor(s, 16); s += __shfl_xor(s, 32);
        q += __shfl_xor(q, 16); q += __shfl_xor(q, 32);
        if (lane < 16) {
            int col = col0 + wc * 64 + ni * 16 + rr;
            atomicAdd(stout + col, s);
            atomicAdd(stout + 512 + col, q);
        }
    }
}

// ---------- selfcorr: BN1+ReLU on staging (coefs from stats), 4x4 patch + 8x8 halo -> gs ----------
#define RSTEP(S, HALF)                                                            \
    _Pragma("unroll") for (int i_ = 0; i_ < HALF; ++i_) {                         \
        float lo_ = p[i_], hi_ = p[HALF + i_];                                    \
        float send_ = (lane & S) ? lo_ : hi_;                                     \
        float keep_ = (lane & S) ? hi_ : lo_;                                     \
        p[i_] = keep_ + __shfl_xor(send_, S);                                     \
    }

__global__ __launch_bounds__(256) void selfcorr2(const ushort* __restrict__ y1, ushort* __restrict__ gs,
                                                 const float* __restrict__ st,
                                                 const float* __restrict__ gamma, const float* __restrict__ beta) {
    __shared__ ushort hl[64 * 512];        // 8x8 halo rows x 512 ch, post-BN bf16
    int h = blockIdx.x;                    // 4096 blocks; XCD swizzle for halo L2 reuse
    int xcd = h & 7, slot = h >> 3;
    int flat = xcd * 512 + slot;
    int bz = flat >> 8, rem = flat & 255;
    int y0 = (rem >> 4) * 4, x0 = (rem & 15) * 4;

    int t = threadIdx.x, wv = t >> 6, lane = t & 63;

    float scv[8], shv[8];
#pragma unroll
    for (int i = 0; i < 8; ++i) {
        int c = lane * 8 + i;
        float mean = st[c] * (1.f / 65536.f);
        float var = st[512 + c] * (1.f / 65536.f) - mean * mean;
        float rs = rsqrtf(var + 1e-5f);
        float s = rs * gamma[c];
        scv[i] = s; shv[i] = beta[c] - mean * s;
    }

#pragma unroll
    for (int i = 0; i < 16; ++i) {
        int rid = i * 4 + wv;              // wave reads one contiguous 1KB row
        int ry = rid >> 3, rx = rid & 7;
        int y = y0 - 2 + ry, x = x0 - 2 + rx;
        uint4 w4 = {0u, 0u, 0u, 0u};
        if (y >= 0 && y < 64 && x >= 0 && x < 64) {
            int n2 = (bz << 12) + (y << 6) + x;
            uint4 v = *(const uint4*)(y1 + (size_t)n2 * 512 + lane * 8);
            float a0 = fmaxf(bf2f(v.x & 0xffffu) * scv[0] + shv[0], 0.f);
            float a1 = fmaxf(bf2f(v.x >> 16)     * scv[1] + shv[1], 0.f);
            float a2 = fmaxf(bf2f(v.y & 0xffffu) * scv[2] + shv[2], 0.f);
            float a3 = fmaxf(bf2f(v.y >> 16)     * scv[3] + shv[3], 0.f);
            float a4 = fmaxf(bf2f(v.z & 0xffffu) * scv[4] + shv[4], 0.f);
            float a5 = fmaxf(bf2f(v.z >> 16)     * scv[5] + shv[5], 0.f);
            float a6 = fmaxf(bf2f(v.w & 0xffffu) * scv[6] + shv[6], 0.f);
            float a7 = fmaxf(bf2f(v.w >> 16)     * scv[7] + shv[7], 0.f);
            w4.x = pk2bf(a0, a1);
            w4.y = pk2bf(a2, a3);
            w4.z = pk2bf(a4, a5);
            w4.w = pk2bf(a6, a7);
        }
        *(uint4*)&hl[rid * 512 + lane * 8] = w4;
    }
    __syncthreads();

    for (int j = 0; j < 4; ++j) {
        int crid = (wv + 2) * 8 + (j + 2);
        uint4 cv = *(const uint4*)&hl[crid * 512 + lane * 8];
        float cf[8];
        cf[0] = bf2f(cv.x & 0xffffu); cf[1] = bf2f(cv.x >> 16);
        cf[2] = bf2f(cv.y & 0xffffu); cf[3] = bf2f(cv.y >> 16);
        cf[4] = bf2f(cv.z & 0xffffu); cf[5] = bf2f(cv.z >> 16);
        cf[6] = bf2f(cv.w & 0xffffu); cf[7] = bf2f(cv.w >> 16);

        float p[32];
#pragma unroll
        for (int i = 0; i < 32; ++i) p[i] = 0.f;
#pragma unroll
        for (int tap = 0; tap < 25; ++tap) {
            int dy = tap / 5 - 2, dx = tap % 5 - 2;
            int rid = (wv + 2 + dy) * 8 + (j + 2 + dx);
            uint4 nv = *(const uint4*)&hl[rid * 512 + lane * 8];
            p[tap] = cf[0] * bf2f(nv.x & 0xffffu) + cf[1] * bf2f(nv.x >> 16)
                   + cf[2] * bf2f(nv.y & 0xffffu) + cf[3] * bf2f(nv.y >> 16)
                   + cf[4] * bf2f(nv.z & 0xffffu) + cf[5] * bf2f(nv.z >> 16)
                   + cf[6] * bf2f(nv.w & 0xffffu) + cf[7] * bf2f(nv.w >> 16);
        }
        RSTEP(1, 16) RSTEP(2, 8) RSTEP(4, 4) RSTEP(8, 2) RSTEP(16, 1)
        float d = p[0] + __shfl_xor(p[0], 32);
        float v2 = d * d;
#pragma unroll
        for (int m = 1; m < 64; m <<= 1) v2 += __shfl_xor(v2, m);   // = 2 * sum_t dot^2
        float inv = rsqrtf(0.5f * v2 + 1e-6f);
        int tt = ((lane & 1) << 4) | ((lane & 2) << 2) | (lane & 4) | ((lane & 8) >> 2) | ((lane & 16) >> 4);
        if (lane < 32 && tt < 25) {
            int n2 = (bz << 12) + ((y0 + wv) << 6) + (x0 + j);
            gs[(size_t)n2 * 64 + tt] = f2bf(d * inv);
        }
    }
}

// ---------- final: BN3 (from stats, no ReLU) + 64x64 transpose [n][o] -> (b,o,h,w) fp32 ----------
__global__ __launch_bounds__(256) void finalk(const ushort* __restrict__ y3, const float* __restrict__ st,
                                              const float* __restrict__ gamma, const float* __restrict__ beta,
                                              float* __restrict__ out) {
    __shared__ float T[64][69];                // [o_local][n_local]
    int id = blockIdx.x, t = threadIdx.x;
    int n0 = (id & 1023) * 64, o0 = (id >> 10) * 64;
    int lane = t & 63, wv = t >> 6;

#pragma unroll
    for (int it = 0; it < 2; ++it) {           // read y3: 32 rows/iter, uint4 per 8 lanes
        int nl = it * 32 + wv * 8 + (lane >> 3);
        int c0 = (lane & 7) * 8;
        uint4 v = *(const uint4*)&y3[(size_t)(n0 + nl) * 512 + o0 + c0];
        uint w[4] = {v.x, v.y, v.z, v.w};
#pragma unroll
        for (int j = 0; j < 4; ++j) {
            T[c0 + j * 2][nl]     = bf2f(w[j] & 0xffffu);
            T[c0 + j * 2 + 1][nl] = bf2f(w[j] >> 16);
        }
    }
    __syncthreads();

    int b = n0 >> 12, s0 = n0 & 4095;
#pragma unroll
    for (int it = 0; it < 16; ++it) {
        int o = o0 + it * 4 + wv;
        float mean = st[o] * (1.f / 65536.f);
        float var = st[512 + o] * (1.f / 65536.f) - mean * mean;
        float sc = rsqrtf(var + 1e-5f) * gamma[o];
        float sh = beta[o] - mean * sc;
        out[((size_t)b * 512 + o) * 4096 + s0 + lane] = T[it * 4 + wv][lane] * sc + sh;
    }
}

// ---------- launch ----------
extern "C" void kernel_launch(void* const* d_in, const int* in_sizes, int n_in,
                              void* d_out, int out_size, void* d_ws, size_t ws_size,
                              hipStream_t stream) {
    (void)in_sizes; (void)n_in; (void)out_size; (void)ws_size;
    const float* x     = (const float*)d_in[0];
    const float* w_in  = (const float*)d_in[1];
    const float* g1    = (const float*)d_in[2];
    const float* b1    = (const float*)d_in[3];
    const float* w_emb = (const float*)d_in[4];
    const float* g2    = (const float*)d_in[5];
    const float* b2    = (const float*)d_in[6];
    const float* w_out = (const float*)d_in[7];
    const float* g3    = (const float*)d_in[8];
    const float* b3    = (const float*)d_in[9];
    float* out = (float*)d_out;

    char* ws = (char*)d_ws;
    // layout (bytes):
    //   [0, 64Mi)        y1 raw [65536][512] bf16; dead after gemm2 -> y3 same region
    //   [64Mi, 128Mi)    h2 [65536][512] bf16
    //   [128Mi, 136Mi)   gs [65536][64] bf16 (25 real cols; rest x zero weights)
    //   [136Mi, ...)     bf16 weights + stats(3x1024 f32)
    ushort* y1   = (ushort*)ws;
    ushort* y3   = (ushort*)ws;
    ushort* h2   = (ushort*)(ws + 67108864);
    ushort* gs   = (ushort*)(ws + 134217728);
    char* wb     = ws + 134217728 + 8388608;
    ushort* wbin  = (ushort*)wb;                             // 512*1024*2 = 1048576
    ushort* wbemb = (ushort*)(wb + 1048576);                 // 512*576*2  = 589824
    ushort* wbout = (ushort*)(wb + 1048576 + 589824);        // 512*512*2  = 524288
    float*  stats = (float*)(wb + 1048576 + 589824 + 524288);// 3*1024 f32

    // prep: weight cvt (4224) + zero stats (1)
    prep<<<4225, 256, 0, stream>>>(w_in, w_emb, w_out, wbin, wbemb, wbout, stats);

    // stage 1: conv1x1_in directly from x (TN, 128^2 4-phase, 3 blocks/CU)
    gemm1_tn<<<2048, 256, 0, stream>>>(x, wbin, y1, stats);
    // gs descriptor (BN1+ReLU from stats on staging; reads raw y1)
    selfcorr2<<<4096, 256, 0, stream>>>(y1, gs, stats, g1, b1);

    // stage 2: embeddingFea; A = BN1(y1)+ReLU (reg-staged) ++ gs (async tile 8); K=576
    gemm_reg<<<512, 512, 0, stream>>>(y1, gs, wbemb, h2, 576, 9, stats, g1, b1, stats + 1024);

    // stage 3: conv1x1_out; A = BN2(h2)+ReLU (reg-staged); K=512
    gemm_reg<<<512, 512, 0, stream>>>(h2, gs, wbout, y3, 512, 8, stats + 1024, g2, b2, stats + 2048);

    // BN3 (from stats) + transpose to NCHW fp32
    finalk<<<8192, 256, 0, stream>>>(y3, stats + 2048, g3, b3, out);
}

// Round 14
// 433.994 us; speedup vs baseline: 1.2309x; 1.2309x over previous
//
#include <hip/hip_runtime.h>
#include <hip/hip_bf16.h>

typedef unsigned int uint;
typedef unsigned short ushort;

using s16x8 = __attribute__((ext_vector_type(8))) short;
using f32x4 = __attribute__((ext_vector_type(4))) float;

#define NPIX 65536   // 16 * 64 * 64 pixels

// ---------- helpers ----------
__device__ __forceinline__ ushort f2bf(float f) {
    uint u = __float_as_uint(f);
    u += 0x7fffu + ((u >> 16) & 1u);   // RNE
    return (ushort)(u >> 16);
}
__device__ __forceinline__ float bf2f(uint h) { return __uint_as_float(h << 16); }
__device__ __forceinline__ uint pk2bf(float a, float b) {      // v_cvt_pk_bf16_f32 (RNE)
    float2 f2; f2.x = a; f2.y = b;
    __hip_bfloat162 h = __float22bfloat162_rn(f2);
    return *(reinterpret_cast<uint*>(&h));
}

__device__ __forceinline__ void async16(const void* g, void* l) {
    __builtin_amdgcn_global_load_lds(
        (const __attribute__((address_space(1))) void*)g,
        (__attribute__((address_space(3))) void*)l, 16, 0, 0);
}

#define VMW4 asm volatile("s_waitcnt vmcnt(4)" ::: "memory")
#define VMW0 asm volatile("s_waitcnt vmcnt(0)" ::: "memory")
#define LKM0 asm volatile("s_waitcnt lgkmcnt(0)" ::: "memory")
#define NOP2 (void)0

// 8-phase phase macro: 4 A-frag ds_reads, stage stmt, optional vmcnt,
// barrier, prio-wrapped 16 MFMA, barrier.  (T3+T4+T5 per guide §5.5)
#define DOPH(m0_, m1_, STG, VMW) do {                                             \
        s16x8 af0_[2], af1_[2];                                                   \
        af0_[0] = AFR(m0_, 0); af0_[1] = AFR(m0_, 1);                             \
        af1_[0] = AFR(m1_, 0); af1_[1] = AFR(m1_, 1);                             \
        STG;                                                                      \
        VMW;                                                                      \
        __builtin_amdgcn_s_barrier();                                             \
        __builtin_amdgcn_s_setprio(1);                                            \
        _Pragma("unroll") for (int ni_ = 0; ni_ < 4; ++ni_) {                     \
            _Pragma("unroll") for (int ks_ = 0; ks_ < 2; ++ks_)                   \
                acc[m0_][ni_] = __builtin_amdgcn_mfma_f32_16x16x32_bf16(          \
                    af0_[ks_], bfr[ni_][ks_], acc[m0_][ni_], 0, 0, 0);            \
            _Pragma("unroll") for (int ks_ = 0; ks_ < 2; ++ks_)                   \
                acc[m1_][ni_] = __builtin_amdgcn_mfma_f32_16x16x32_bf16(          \
                    af1_[ks_], bfr[ni_][ks_], acc[m1_][ni_], 0, 0, 0);            \
        }                                                                         \
        __builtin_amdgcn_s_setprio(0);                                            \
        __builtin_amdgcn_s_barrier();                                             \
    } while (0)

// ---------- prep: weight cvt (w_emb padded to 576) + stats zero ----------
__global__ __launch_bounds__(256) void prep(const float* __restrict__ w_in, const float* __restrict__ w_emb,
                                            const float* __restrict__ w_out,
                                            ushort* __restrict__ o1, ushort* __restrict__ o2,
                                            ushort* __restrict__ o3, float* __restrict__ stats) {
    int id = blockIdx.x, t = threadIdx.x;
    if (id < 4224) {                                   // weight convert
        int i = id * 256 + t;
        if (i < 524288) {                              // w_in 512x1024
            o1[i] = f2bf(w_in[i]);
        } else if (i < 819200) {                       // w_emb 512x576 (537 real, pad 0)
            int j = i - 524288;
            int r = j / 576, c = j - r * 576;
            o2[j] = (c < 537) ? f2bf(w_emb[(size_t)r * 537 + c]) : (ushort)0;
        } else {                                       // w_out 512x512
            int j = i - 819200;
            o3[j] = f2bf(w_out[j]);
        }
    } else {                                           // zero stats (3*1024 f32)
#pragma unroll
        for (int r = 0; r < 12; ++r) stats[r * 256 + t] = 0.f;
    }
}

// ---------- GEMM1 (TN): A = x NCHW fp32 in-place, 8-phase engine (R11, 158us) ----------
__global__ __launch_bounds__(512, 2) void gemm1_tn(const float* __restrict__ x, const ushort* __restrict__ Bw,
                                                   ushort* __restrict__ C, float* __restrict__ st) {
    const int K = 1024, NT = 16;
    __shared__ ushort Asm[2][2][128][64];
    __shared__ ushort Bsm[2][2][128][64];

    int id = blockIdx.x;                       // 512 blocks
    int swz = (id & 7) * 64 + (id >> 3);       // XCD x owns swz [x*64, x*64+64)
    int row0 = (swz >> 1) * 256, col0 = (swz & 1) * 256;

    int t = threadIdx.x, wv = t >> 6, lane = t & 63;
    int wr = wv >> 2, wc = wv & 3;             // wave grid 2M x 4N
    int g = lane >> 4, rr = lane & 15;
    int swzl = (rr & 7) << 4;

    // B staging (async, pre-swizzled source)
    int srow = t >> 3;
    int scol = ((t & 7) * 16) ^ ((srow & 7) << 4);
    const ushort* pb = Bw + (size_t)(col0 + srow) * K + (scol >> 1);

    // A staging from x: thread covers c = c0..c0+3, s = srel..srel+3 (both halves)
    int c0 = (lane & 15) * 4;
    int srel = wv * 16 + (lane >> 4) * 4;
    const float* px = x + (((size_t)(row0 >> 12) * 1024) << 12) + (row0 & 4095) + srel;

    const f32x4 fz = {0.f, 0.f, 0.f, 0.f};
    f32x4 acc[8][4];
#pragma unroll
    for (int i = 0; i < 8; ++i)
#pragma unroll
        for (int j = 0; j < 4; ++j) acc[i][j] = fz;

    float4 LA[2][4];

#define STB(d_, h_, kt_) do {                                                     \
        async16(pb + (size_t)((h_) * 128) * K + (kt_) * 64,      &Bsm[d_][h_][wv * 8][0]);      \
        async16(pb + (size_t)((h_) * 128 + 64) * K + (kt_) * 64, &Bsm[d_][h_][64 + wv * 8][0]); \
    } while (0)
#define LOADX(kt_) do {                                                           \
        _Pragma("unroll") for (int h_ = 0; h_ < 2; ++h_)                          \
        _Pragma("unroll") for (int i_ = 0; i_ < 4; ++i_)                          \
            LA[h_][i_] = *(const float4*)&px[(((size_t)((kt_) * 64 + c0 + i_)) << 12) + h_ * 128]; \
    } while (0)
#define WRITEX(e_) do {                                                           \
        _Pragma("unroll") for (int h_ = 0; h_ < 2; ++h_)                          \
        _Pragma("unroll") for (int j_ = 0; j_ < 4; ++j_) {                        \
            int r_ = srel + j_;                                                   \
            float e0_ = ((const float*)&LA[h_][0])[j_];                           \
            float e1_ = ((const float*)&LA[h_][1])[j_];                           \
            float e2_ = ((const float*)&LA[h_][2])[j_];                           \
            float e3_ = ((const float*)&LA[h_][3])[j_];                           \
            uint2 pk_;                                                            \
            pk_.x = pk2bf(e0_, e1_);                                              \
            pk_.y = pk2bf(e2_, e3_);                                              \
            *(uint2*)&Asm[e_][h_][r_][((c0 * 2) ^ ((r_ & 7) << 4)) >> 1] = pk_;   \
        }                                                                         \
    } while (0)
#define AFR(m_, ks_) (*(const s16x8*)&Asm[d][wr][(m_) * 16 + rr][(((ks_) * 64 + g * 16) ^ swzl) >> 1])

    // prologue: A(0) reg-staged, B(0)+B(1) async; vmcnt(4) -> B(0) landed, B(1) in flight
    LOADX(0);
    STB(0, 0, 0); STB(0, 1, 0); STB(1, 0, 1); STB(1, 1, 1);
    WRITEX(0);
    VMW4;
    LKM0;
    __builtin_amdgcn_s_barrier();

    for (int kt = 0; kt < NT; ++kt) {
        int d = kt & 1, e = d ^ 1;
        s16x8 bfr[4][2];
#pragma unroll
        for (int ni = 0; ni < 4; ++ni)
#pragma unroll
            for (int ks = 0; ks < 2; ++ks)
                bfr[ni][ks] = *(const s16x8*)&Bsm[d][wc >> 1][(wc & 1) * 64 + ni * 16 + rr][((ks * 64 + g * 16) ^ swzl) >> 1];
        DOPH(0, 1, if (kt + 1 < NT) LOADX(kt + 1), NOP2);
        DOPH(2, 3, NOP2, NOP2);
        DOPH(4, 5, { if (kt + 1 < NT) WRITEX(e); if (kt + 2 < NT) STB(d, 0, kt + 2); }, NOP2);
        DOPH(6, 7, if (kt + 2 < NT) STB(d, 1, kt + 2), VMW4);
    }
#undef STB
#undef LOADX
#undef WRITEX
#undef AFR

    // C write (C/D layout: col = lane&15, row = (lane>>4)*4 + reg) + fused stats
#pragma unroll
    for (int mi = 0; mi < 8; ++mi)
#pragma unroll
        for (int ni = 0; ni < 4; ++ni)
#pragma unroll
            for (int e2 = 0; e2 < 4; ++e2) {
                int row = row0 + wr * 128 + mi * 16 + g * 4 + e2;
                int col = col0 + wc * 64 + ni * 16 + rr;
                C[(size_t)row * 512 + col] = f2bf(acc[mi][ni][e2]);
            }
#pragma unroll
    for (int ni = 0; ni < 4; ++ni) {
        float s = 0.f, q = 0.f;
#pragma unroll
        for (int mi = 0; mi < 8; ++mi)
#pragma unroll
            for (int e2 = 0; e2 < 4; ++e2) {
                float v = acc[mi][ni][e2];
                s += v; q += v * v;
            }
        s += __shfl_xor(s, 16); s += __shfl_xor(s, 32);
        q += __shfl_xor(q, 16); q += __shfl_xor(q, 32);
        if (lane < 16) {
            int col = col0 + wc * 64 + ni * 16 + rr;
            atomicAdd(st + col, s);
            atomicAdd(st + 512 + col, q);
        }
    }
}

// ---------- GEMM2/3: 8-phase engine + reg-staged A with fused BN+ReLU; gs tile async ----------
// NT=9 (K=576, gs cols 512..575) for gemm2; NT=8 (K=512) for gemm3.  Tail vmcnt(0) at
// kt==NT-2 guarantees the GSTAGE/last-B tile landed before its read (closes latent race).
__global__ __launch_bounds__(512, 2) void gemm_reg(const ushort* __restrict__ Araw, const ushort* __restrict__ gsrc,
                                                   const ushort* __restrict__ Bw, ushort* __restrict__ C,
                                                   int Kb, int NT,
                                                   const float* __restrict__ stin, const float* __restrict__ gamma,
                                                   const float* __restrict__ beta, float* __restrict__ stout) {
    __shared__ ushort Asm[2][2][128][64];
    __shared__ ushort Bsm[2][2][128][64];

    int id = blockIdx.x;
    int swz = (id & 7) * 64 + (id >> 3);
    int row0 = (swz >> 1) * 256, col0 = (swz & 1) * 256;

    int t = threadIdx.x, wv = t >> 6, lane = t & 63;
    int wr = wv >> 2, wc = wv & 3;
    int g = lane >> 4, rr = lane & 15;
    int swzl = (rr & 7) << 4;

    int srow = t >> 3;
    int kb = (t & 7) * 16;                         // logical col byte within 128B k-row
    int scol = kb ^ ((srow & 7) << 4);             // pre-swizzled (async paths)
    const ushort* pb = Bw + (size_t)(col0 + srow) * Kb + (scol >> 1);
    const ushort* pg = gsrc + (size_t)(row0 + srow) * 64 + (scol >> 1);
    int wofs = scol >> 1;                          // swizzled LDS elem offset for reg writes

    const f32x4 fz = {0.f, 0.f, 0.f, 0.f};
    f32x4 acc[8][4];
#pragma unroll
    for (int i = 0; i < 8; ++i)
#pragma unroll
        for (int j = 0; j < 4; ++j) acc[i][j] = fz;

    uint4 rq0, rq1, rq2, rq3;
    float scq[8], shq[8];

#define STB(d_, h_, kt_) do {                                                     \
        async16(pb + (size_t)((h_) * 128) * Kb + (kt_) * 64,      &Bsm[d_][h_][wv * 8][0]);      \
        async16(pb + (size_t)((h_) * 128 + 64) * Kb + (kt_) * 64, &Bsm[d_][h_][64 + wv * 8][0]); \
    } while (0)
#define GSTAGE(d_) do {                                                           \
        async16(pg,             &Asm[d_][0][wv * 8][0]);                          \
        async16(pg + 64 * 64,   &Asm[d_][0][64 + wv * 8][0]);                     \
        async16(pg + 128 * 64,  &Asm[d_][1][wv * 8][0]);                          \
        async16(pg + 192 * 64,  &Asm[d_][1][64 + wv * 8][0]);                     \
    } while (0)
#define LOADQ(kt_) do { int c0_ = (kt_) * 64 + (t & 7) * 8;                       \
        float4 m1_ = *(const float4*)&stin[c0_], m2_ = *(const float4*)&stin[c0_ + 4]; \
        float4 v1_ = *(const float4*)&stin[512 + c0_], v2_ = *(const float4*)&stin[512 + c0_ + 4]; \
        float4 g1_ = *(const float4*)&gamma[c0_], g2_ = *(const float4*)&gamma[c0_ + 4]; \
        float4 b1_ = *(const float4*)&beta[c0_],  b2_ = *(const float4*)&beta[c0_ + 4]; \
        float mm_[8] = {m1_.x, m1_.y, m1_.z, m1_.w, m2_.x, m2_.y, m2_.z, m2_.w};  \
        float vv_[8] = {v1_.x, v1_.y, v1_.z, v1_.w, v2_.x, v2_.y, v2_.z, v2_.w};  \
        float gg_[8] = {g1_.x, g1_.y, g1_.z, g1_.w, g2_.x, g2_.y, g2_.z, g2_.w};  \
        float bb_[8] = {b1_.x, b1_.y, b1_.z, b1_.w, b2_.x, b2_.y, b2_.z, b2_.w};  \
        _Pragma("unroll") for (int j_ = 0; j_ < 8; ++j_) {                        \
            float mean_ = mm_[j_] * (1.f / 65536.f);                              \
            float var_ = vv_[j_] * (1.f / 65536.f) - mean_ * mean_;               \
            float s_ = rsqrtf(var_ + 1e-5f) * gg_[j_];                            \
            scq[j_] = s_; shq[j_] = bb_[j_] - mean_ * s_;                         \
        }                                                                         \
        const ushort* pa_ = Araw + (size_t)(row0 + srow) * 512 + c0_;             \
        rq0 = *(const uint4*)(pa_);                                               \
        rq1 = *(const uint4*)(pa_ + 64 * 512);                                    \
        rq2 = *(const uint4*)(pa_ + 128 * 512);                                   \
        rq3 = *(const uint4*)(pa_ + 192 * 512);                                   \
    } while (0)
#define XFORM1(rv) do {                                                           \
        uint w_[4]; uint in_[4] = {rv.x, rv.y, rv.z, rv.w};                       \
        _Pragma("unroll") for (int p_ = 0; p_ < 4; ++p_) {                        \
            float a_ = fmaxf(bf2f(in_[p_] & 0xffffu) * scq[p_ * 2] + shq[p_ * 2], 0.f); \
            float b_ = fmaxf(bf2f(in_[p_] >> 16) * scq[p_ * 2 + 1] + shq[p_ * 2 + 1], 0.f); \
            w_[p_] = pk2bf(a_, b_);                                               \
        }                                                                         \
        rv.x = w_[0]; rv.y = w_[1]; rv.z = w_[2]; rv.w = w_[3];                   \
    } while (0)
#define WRITEQ(d_) do {                                                           \
        XFORM1(rq0); XFORM1(rq1); XFORM1(rq2); XFORM1(rq3);                       \
        *(uint4*)&Asm[d_][0][srow][wofs]      = rq0;                              \
        *(uint4*)&Asm[d_][0][srow + 64][wofs] = rq1;                              \
        *(uint4*)&Asm[d_][1][srow][wofs]      = rq2;                              \
        *(uint4*)&Asm[d_][1][srow + 64][wofs] = rq3;                              \
    } while (0)
#define AFR(m_, ks_) (*(const s16x8*)&Asm[d][wr][(m_) * 16 + rr][(((ks_) * 64 + g * 16) ^ swzl) >> 1])

    LOADQ(0);
    STB(0, 0, 0); STB(0, 1, 0); STB(1, 0, 1); STB(1, 1, 1);
    WRITEQ(0);
    VMW4;
    LKM0;
    __builtin_amdgcn_s_barrier();

    for (int kt = 0; kt < NT; ++kt) {
        int d = kt & 1, e = d ^ 1;
        s16x8 bfr[4][2];
#pragma unroll
        for (int ni = 0; ni < 4; ++ni)
#pragma unroll
            for (int ks = 0; ks < 2; ++ks)
                bfr[ni][ks] = *(const s16x8*)&Bsm[d][wc >> 1][(wc & 1) * 64 + ni * 16 + rr][((ks * 64 + g * 16) ^ swzl) >> 1];
        DOPH(0, 1, { if (kt + 1 < NT) { if (kt + 1 < 8) LOADQ(kt + 1); else GSTAGE(e); } }, NOP2);
        DOPH(2, 3, NOP2, NOP2);
        DOPH(4, 5, { if (kt + 1 < 8) WRITEQ(e); if (kt + 2 < NT) STB(d, 0, kt + 2); }, NOP2);
        DOPH(6, 7, if (kt + 2 < NT) STB(d, 1, kt + 2), { if (kt == NT - 2) { VMW0; } else { VMW4; } });
    }
#undef STB
#undef GSTAGE
#undef LOADQ
#undef XFORM1
#undef WRITEQ
#undef AFR

#pragma unroll
    for (int mi = 0; mi < 8; ++mi)
#pragma unroll
        for (int ni = 0; ni < 4; ++ni)
#pragma unroll
            for (int e2 = 0; e2 < 4; ++e2) {
                int row = row0 + wr * 128 + mi * 16 + g * 4 + e2;
                int col = col0 + wc * 64 + ni * 16 + rr;
                C[(size_t)row * 512 + col] = f2bf(acc[mi][ni][e2]);
            }
#pragma unroll
    for (int ni = 0; ni < 4; ++ni) {
        float s = 0.f, q = 0.f;
#pragma unroll
        for (int mi = 0; mi < 8; ++mi)
#pragma unroll
            for (int e2 = 0; e2 < 4; ++e2) {
                float v = acc[mi][ni][e2];
                s += v; q += v * v;
            }
        s += __shfl_xor(s, 16); s += __shfl_xor(s, 32);
        q += __shfl_xor(q, 16); q += __shfl_xor(q, 32);
        if (lane < 16) {
            int col = col0 + wc * 64 + ni * 16 + rr;
            atomicAdd(stout + col, s);
            atomicAdd(stout + 512 + col, q);
        }
    }
}

// ---------- selfcorr: BN1+ReLU on staging (coefs from stats), 4x4 patch + 8x8 halo -> gs[64] ----------
#define RSTEP(S, HALF)                                                            \
    _Pragma("unroll") for (int i_ = 0; i_ < HALF; ++i_) {                         \
        float lo_ = p[i_], hi_ = p[HALF + i_];                                    \
        float send_ = (lane & S) ? lo_ : hi_;                                     \
        float keep_ = (lane & S) ? hi_ : lo_;                                     \
        p[i_] = keep_ + __shfl_xor(send_, S);                                     \
    }

__global__ __launch_bounds__(256) void selfcorr2(const ushort* __restrict__ y1, ushort* __restrict__ gs,
                                                 const float* __restrict__ st,
                                                 const float* __restrict__ gamma, const float* __restrict__ beta) {
    __shared__ ushort hl[64 * 512];        // 8x8 halo rows x 512 ch, post-BN bf16
    int h = blockIdx.x;                    // 4096 blocks; XCD swizzle for halo L2 reuse
    int xcd = h & 7, slot = h >> 3;
    int flat = xcd * 512 + slot;
    int bz = flat >> 8, rem = flat & 255;
    int y0 = (rem >> 4) * 4, x0 = (rem & 15) * 4;

    int t = threadIdx.x, wv = t >> 6, lane = t & 63;

    float scv[8], shv[8];
#pragma unroll
    for (int i = 0; i < 8; ++i) {
        int c = lane * 8 + i;
        float mean = st[c] * (1.f / 65536.f);
        float var = st[512 + c] * (1.f / 65536.f) - mean * mean;
        float rs = rsqrtf(var + 1e-5f);
        float s = rs * gamma[c];
        scv[i] = s; shv[i] = beta[c] - mean * s;
    }

#pragma unroll
    for (int i = 0; i < 16; ++i) {
        int rid = i * 4 + wv;              // wave reads one contiguous 1KB row
        int ry = rid >> 3, rx = rid & 7;
        int y = y0 - 2 + ry, x = x0 - 2 + rx;
        uint4 w4 = {0u, 0u, 0u, 0u};
        if (y >= 0 && y < 64 && x >= 0 && x < 64) {
            int n2 = (bz << 12) + (y << 6) + x;
            uint4 v = *(const uint4*)(y1 + (size_t)n2 * 512 + lane * 8);
            float a0 = fmaxf(bf2f(v.x & 0xffffu) * scv[0] + shv[0], 0.f);
            float a1 = fmaxf(bf2f(v.x >> 16)     * scv[1] + shv[1], 0.f);
            float a2 = fmaxf(bf2f(v.y & 0xffffu) * scv[2] + shv[2], 0.f);
            float a3 = fmaxf(bf2f(v.y >> 16)     * scv[3] + shv[3], 0.f);
            float a4 = fmaxf(bf2f(v.z & 0xffffu) * scv[4] + shv[4], 0.f);
            float a5 = fmaxf(bf2f(v.z >> 16)     * scv[5] + shv[5], 0.f);
            float a6 = fmaxf(bf2f(v.w & 0xffffu) * scv[6] + shv[6], 0.f);
            float a7 = fmaxf(bf2f(v.w >> 16)     * scv[7] + shv[7], 0.f);
            w4.x = pk2bf(a0, a1);
            w4.y = pk2bf(a2, a3);
            w4.z = pk2bf(a4, a5);
            w4.w = pk2bf(a6, a7);
        }
        *(uint4*)&hl[rid * 512 + lane * 8] = w4;
    }
    __syncthreads();

    for (int j = 0; j < 4; ++j) {
        int crid = (wv + 2) * 8 + (j + 2);
        uint4 cv = *(const uint4*)&hl[crid * 512 + lane * 8];
        float cf[8];
        cf[0] = bf2f(cv.x & 0xffffu); cf[1] = bf2f(cv.x >> 16);
        cf[2] = bf2f(cv.y & 0xffffu); cf[3] = bf2f(cv.y >> 16);
        cf[4] = bf2f(cv.z & 0xffffu); cf[5] = bf2f(cv.z >> 16);
        cf[6] = bf2f(cv.w & 0xffffu); cf[7] = bf2f(cv.w >> 16);

        float p[32];
#pragma unroll
        for (int i = 0; i < 32; ++i) p[i] = 0.f;
#pragma unroll
        for (int tap = 0; tap < 25; ++tap) {
            int dy = tap / 5 - 2, dx = tap % 5 - 2;
            int rid = (wv + 2 + dy) * 8 + (j + 2 + dx);
            uint4 nv = *(const uint4*)&hl[rid * 512 + lane * 8];
            p[tap] = cf[0] * bf2f(nv.x & 0xffffu) + cf[1] * bf2f(nv.x >> 16)
                   + cf[2] * bf2f(nv.y & 0xffffu) + cf[3] * bf2f(nv.y >> 16)
                   + cf[4] * bf2f(nv.z & 0xffffu) + cf[5] * bf2f(nv.z >> 16)
                   + cf[6] * bf2f(nv.w & 0xffffu) + cf[7] * bf2f(nv.w >> 16);
        }
        RSTEP(1, 16) RSTEP(2, 8) RSTEP(4, 4) RSTEP(8, 2) RSTEP(16, 1)
        float d = p[0] + __shfl_xor(p[0], 32);
        float v2 = d * d;
#pragma unroll
        for (int m = 1; m < 64; m <<= 1) v2 += __shfl_xor(v2, m);   // = 2 * sum_t dot^2
        float inv = rsqrtf(0.5f * v2 + 1e-6f);
        int tt = ((lane & 1) << 4) | ((lane & 2) << 2) | (lane & 4) | ((lane & 8) >> 2) | ((lane & 16) >> 4);
        if (lane < 32 && tt < 25) {
            int n2 = (bz << 12) + ((y0 + wv) << 6) + (x0 + j);
            gs[(size_t)n2 * 64 + tt] = f2bf(d * inv);
        }
    }
}

// ---------- final: BN3 (from stats, no ReLU) + 64x64 transpose [n][o] -> (b,o,h,w) fp32 ----------
__global__ __launch_bounds__(256) void finalk(const ushort* __restrict__ y3, const float* __restrict__ st,
                                              const float* __restrict__ gamma, const float* __restrict__ beta,
                                              float* __restrict__ out) {
    __shared__ float T[64][69];                // [o_local][n_local]
    int id = blockIdx.x, t = threadIdx.x;
    int n0 = (id & 1023) * 64, o0 = (id >> 10) * 64;
    int lane = t & 63, wv = t >> 6;

#pragma unroll
    for (int it = 0; it < 2; ++it) {           // read y3: 32 rows/iter, uint4 per 8 lanes
        int nl = it * 32 + wv * 8 + (lane >> 3);
        int c0 = (lane & 7) * 8;
        uint4 v = *(const uint4*)&y3[(size_t)(n0 + nl) * 512 + o0 + c0];
        uint w[4] = {v.x, v.y, v.z, v.w};
#pragma unroll
        for (int j = 0; j < 4; ++j) {
            T[c0 + j * 2][nl]     = bf2f(w[j] & 0xffffu);
            T[c0 + j * 2 + 1][nl] = bf2f(w[j] >> 16);
        }
    }
    __syncthreads();

    int b = n0 >> 12, s0 = n0 & 4095;
#pragma unroll
    for (int it = 0; it < 16; ++it) {
        int o = o0 + it * 4 + wv;
        float mean = st[o] * (1.f / 65536.f);
        float var = st[512 + o] * (1.f / 65536.f) - mean * mean;
        float sc = rsqrtf(var + 1e-5f) * gamma[o];
        float sh = beta[o] - mean * sc;
        out[((size_t)b * 512 + o) * 4096 + s0 + lane] = T[it * 4 + wv][lane] * sc + sh;
    }
}

// ---------- launch ----------
extern "C" void kernel_launch(void* const* d_in, const int* in_sizes, int n_in,
                              void* d_out, int out_size, void* d_ws, size_t ws_size,
                              hipStream_t stream) {
    (void)in_sizes; (void)n_in; (void)out_size; (void)ws_size;
    const float* x     = (const float*)d_in[0];
    const float* w_in  = (const float*)d_in[1];
    const float* g1    = (const float*)d_in[2];
    const float* b1    = (const float*)d_in[3];
    const float* w_emb = (const float*)d_in[4];
    const float* g2    = (const float*)d_in[5];
    const float* b2    = (const float*)d_in[6];
    const float* w_out = (const float*)d_in[7];
    const float* g3    = (const float*)d_in[8];
    const float* b3    = (const float*)d_in[9];
    float* out = (float*)d_out;

    char* ws = (char*)d_ws;
    // layout (bytes):
    //   [0, 64Mi)        y1 raw [65536][512] bf16; dead after gemm2 -> y3 same region
    //   [64Mi, 128Mi)    h2 [65536][512] bf16
    //   [128Mi, 136Mi)   gs [65536][64] bf16 (25 real cols; rest x zero weights)
    //   [136Mi, ...)     bf16 weights + stats(3x1024 f32)
    ushort* y1   = (ushort*)ws;
    ushort* y3   = (ushort*)ws;
    ushort* h2   = (ushort*)(ws + 67108864);
    ushort* gs   = (ushort*)(ws + 134217728);
    char* wb     = ws + 134217728 + 8388608;
    ushort* wbin  = (ushort*)wb;                             // 512*1024*2 = 1048576
    ushort* wbemb = (ushort*)(wb + 1048576);                 // 512*576*2  = 589824
    ushort* wbout = (ushort*)(wb + 1048576 + 589824);        // 512*512*2  = 524288
    float*  stats = (float*)(wb + 1048576 + 589824 + 524288);// 3*1024 f32

    // prep: weight cvt (4224) + zero stats (1)
    prep<<<4225, 256, 0, stream>>>(w_in, w_emb, w_out, wbin, wbemb, wbout, stats);

    // stage 1: conv1x1_in directly from x (TN, 8-phase engine, R11)
    gemm1_tn<<<512, 512, 0, stream>>>(x, wbin, y1, stats);
    // gs descriptor (BN1+ReLU from stats on staging; reads raw y1)
    selfcorr2<<<4096, 256, 0, stream>>>(y1, gs, stats, g1, b1);

    // stage 2: embeddingFea; A = BN1(y1)+ReLU (reg-staged) ++ gs (async tile 8); K=576
    gemm_reg<<<512, 512, 0, stream>>>(y1, gs, wbemb, h2, 576, 9, stats, g1, b1, stats + 1024);

    // stage 3: conv1x1_out; A = BN2(h2)+ReLU (reg-staged); K=512
    gemm_reg<<<512, 512, 0, stream>>>(h2, gs, wbout, y3, 512, 8, stats + 1024, g2, b2, stats + 2048);

    // BN3 (from stats) + transpose to NCHW fp32
    finalk<<<8192, 256, 0, stream>>>(y3, stats + 2048, g3, b3, out);
}